// Round 6
// baseline (144.334 us; speedup 1.0000x reference)
//
#include <hip/hip_runtime.h>
#include <hip/hip_bf16.h>

// CrossAttention fused pipeline, MI355X (gfx950)
// B=2, N=160, D=4096, H=4, DH=1024, SCALE=1/32 (applied twice)
//
// Stage 0: cvt x,y f32 -> bf16
// Stage 1+2: weight-stationary GEMM, ZERO-barrier main loop:
//   wave tile = 160 rows x 32 cols x Kc=1024 (K-split over the 4 waves of a
//   block). A-frags and W-frags go global->register directly (no LDS, no
//   barriers, no vmcnt drains). W f32 loads parity-double-buffered in regs.
//   Block epilogue: 4-wave K-reduction through a 42 KB LDS tile (2 barriers
//   total), writes qT[b][d][n] (z=0, transposed) and k[320][4096] (z=1).
// Stage 3: kkt = SCALE * k.k^T per (b,h)      (bf16)
// Stage 4: out = softplus(SCALE * qT @ kkt^T) (f32)

typedef __attribute__((ext_vector_type(4))) float  f32x4;
typedef __attribute__((ext_vector_type(8))) __bf16 bf16x8;

#define SCALE 0.03125f

static __device__ __forceinline__ f32x4 mfma16(bf16x8 a, bf16x8 b, f32x4 c) {
    return __builtin_amdgcn_mfma_f32_16x16x32_bf16(a, b, c, 0, 0, 0);
}

static __device__ __forceinline__ bf16x8 pack8(float4 a, float4 b) {
    bf16x8 r;
    r[0] = (__bf16)a.x; r[1] = (__bf16)a.y; r[2] = (__bf16)a.z; r[3] = (__bf16)a.w;
    r[4] = (__bf16)b.x; r[5] = (__bf16)b.y; r[6] = (__bf16)b.z; r[7] = (__bf16)b.w;
    return r;
}

static __device__ __forceinline__ float softplus(float x) {
    return fmaxf(x, 0.0f) + log1pf(expf(-fabsf(x)));
}

// ---------------------------------------------------------------------------
// Stage 0: f32 -> bf16 conversion of activations. grid (640, 2), 256 thr.
// ---------------------------------------------------------------------------
__global__ __launch_bounds__(256)
void cvt_kernel(const float* __restrict__ x, const float* __restrict__ y,
                __bf16* __restrict__ xb, __bf16* __restrict__ yb)
{
    const float* src = blockIdx.y ? y : x;
    __bf16* dst = blockIdx.y ? yb : xb;
    size_t i = ((size_t)blockIdx.x * 256 + threadIdx.x) * 8;
    float4 a = *(const float4*)(src + i);
    float4 b = *(const float4*)(src + i + 4);
    *(bf16x8*)(dst + i) = pack8(a, b);
}

// ---------------------------------------------------------------------------
// Stage 1+2: barrier-free weight-stationary GEMM.
// grid 512 blocks x 256 threads. Block = one 32-col W panel x (z, mh);
// its 4 waves split K (wave w: K in [w*1024, (w+1)*1024)).
// Per K=32 step per wave: 10 A-frag loads (bf16x8, L2-hot), 4 W float4
// loads (HBM/L3, parity-dbuf in regs), 8 cvt_pk, 20 MFMA. No LDS/barriers.
// Epilogue: K-reduce across waves via LDS (2 barriers), store bf16.
// Block swizzle: blockIdx&7 = (z<<2)|panel_low2 -> XCD key, so each XCD
// keeps one z's A slab (2.6 MB) + its W panels in L2; mh pairs co-located.
// ---------------------------------------------------------------------------
__global__ __launch_bounds__(256, 2)
void qk_gemm(const __bf16* __restrict__ yb, const __bf16* __restrict__ xb,
             const float* __restrict__ Wq, const float* __restrict__ Wk,
             __bf16* __restrict__ qT, __bf16* __restrict__ kout)
{
    const int b7    = blockIdx.x & 7;
    const int z     = b7 >> 2;
    const int plow  = b7 & 3;
    const int rest  = blockIdx.x >> 3;
    const int mh    = rest & 1;                 // batch half
    const int panel = (rest >> 1) * 4 + plow;   // 0..127
    const int bn    = panel * 32;

    const int tid  = threadIdx.x;
    const int lane = tid & 63;
    const int wid  = tid >> 6;                  // wave = K-chunk index
    const int kc0  = wid << 10;

    const __bf16* __restrict__ Ab = (z ? xb : yb) + (size_t)mh * 160 * 4096;
    const float*  __restrict__ Wm = z ? Wk : Wq;

    const int li = lane & 15;                   // frag row/col
    const int lk = lane >> 4;                   // k sub-chunk

    const __bf16* ap  = Ab + (size_t)li * 4096 + kc0 + lk * 8;
    const float*  wp0 = Wm + (size_t)(bn + li) * 4096 + kc0 + lk * 8;
    const float*  wp1 = wp0 + (size_t)16 * 4096;

    f32x4 acc[10][2] = {};

    float4 a0, a1, a2, a3;   // parity buffer A (even steps)
    float4 b0, b1, b2, b3;   // parity buffer B (odd steps)

    // prologue: W(0) -> A-buf, W(1) -> B-buf
    a0 = *(const float4*)(wp0);      a1 = *(const float4*)(wp0 + 4);
    a2 = *(const float4*)(wp1);      a3 = *(const float4*)(wp1 + 4);
    b0 = *(const float4*)(wp0 + 32); b1 = *(const float4*)(wp0 + 36);
    b2 = *(const float4*)(wp1 + 32); b3 = *(const float4*)(wp1 + 36);

#define QK_BODY(S, R0, R1, R2, R3)                                          \
    {                                                                        \
        bf16x8 af[10];                                                       \
        _Pragma("unroll")                                                    \
        for (int m = 0; m < 10; ++m)                                         \
            af[m] = *(const bf16x8*)(ap + (size_t)m * 16 * 4096 + (S) * 32); \
        bf16x8 wf0 = pack8(R0, R1);                                          \
        bf16x8 wf1 = pack8(R2, R3);                                          \
        if ((S) < 30) {                                                      \
            R0 = *(const float4*)(wp0 + ((S) + 2) * 32);                     \
            R1 = *(const float4*)(wp0 + ((S) + 2) * 32 + 4);                 \
            R2 = *(const float4*)(wp1 + ((S) + 2) * 32);                     \
            R3 = *(const float4*)(wp1 + ((S) + 2) * 32 + 4);                 \
        }                                                                    \
        _Pragma("unroll")                                                    \
        for (int m = 0; m < 10; ++m) {                                       \
            acc[m][0] = mfma16(af[m], wf0, acc[m][0]);                       \
            acc[m][1] = mfma16(af[m], wf1, acc[m][1]);                       \
        }                                                                    \
    }

    for (int s = 0; s < 32; s += 2) {
        QK_BODY(s,     a0, a1, a2, a3);
        QK_BODY(s + 1, b0, b1, b2, b3);
    }
#undef QK_BODY

    // ---- epilogue: K-reduce the 4 waves via LDS, two phases of 80 rows ----
    __shared__ float red[4][80][33];            // +1 pad; 42.2 KB

    for (int ph = 0; ph < 2; ++ph) {
        if (ph) __syncthreads();                // WAR: phase-0 reads done
        #pragma unroll
        for (int mm = 0; mm < 5; ++mm) {
            const int m = ph * 5 + mm;
            #pragma unroll
            for (int jn = 0; jn < 2; ++jn)
                #pragma unroll
                for (int r = 0; r < 4; ++r)
                    red[wid][mm * 16 + lk * 4 + r][jn * 16 + li] = acc[m][jn][r];
        }
        __syncthreads();

        const int c  = tid & 31;
        const int r0 = (tid >> 5) * 10;
        #pragma unroll
        for (int i = 0; i < 10; ++i) {
            const int rr = r0 + i;
            float v = red[0][rr][c] + red[1][rr][c] + red[2][rr][c] + red[3][rr][c];
            const int grow = ph * 80 + rr;      // 0..159
            const int gcol = bn + c;
            if (z == 0)
                qT[(size_t)mh * 4096 * 160 + (size_t)gcol * 160 + grow] = (__bf16)v;
            else
                kout[(size_t)(mh * 160 + grow) * 4096 + gcol] = (__bf16)v;
        }
    }
}

// ---------------------------------------------------------------------------
// Stage 3: kkt (symmetric). One wave per 16x16 output tile, K=1024.
// ---------------------------------------------------------------------------
__global__ __launch_bounds__(64)
void kkt_kernel(const __bf16* __restrict__ kmat, __bf16* __restrict__ kkt)
{
    const int bh = blockIdx.x;            // b*4 + h
    const int b  = bh >> 2, h = bh & 3;
    const int i0 = blockIdx.y * 16;
    const int j0 = blockIdx.z * 16;
    const int lane = threadIdx.x;

    const __bf16* base = kmat + (size_t)b * 160 * 4096 + h * 1024;
    const int ko = (lane >> 4) << 3;
    const __bf16* pa = base + (size_t)(i0 + (lane & 15)) * 4096 + ko;
    const __bf16* pb = base + (size_t)(j0 + (lane & 15)) * 4096 + ko;

    f32x4 acc = {};
    #pragma unroll 4
    for (int kk = 0; kk < 1024; kk += 32) {
        bf16x8 a  = *(const bf16x8*)(pa + kk);
        bf16x8 bb = *(const bf16x8*)(pb + kk);
        acc = mfma16(a, bb, acc);
    }

    #pragma unroll
    for (int r = 0; r < 4; ++r) {
        int i = i0 + ((lane >> 4) << 2) + r;
        int j = j0 + (lane & 15);
        kkt[((size_t)bh * 160 + i) * 160 + j] = (__bf16)(acc[r] * SCALE);
    }
}

// ---------------------------------------------------------------------------
// Stage 4: dots + softplus. Per (b,h): C(4096x160) = qT[b] @ kkt[b,h]^T. K=160.
// ---------------------------------------------------------------------------
__global__ __launch_bounds__(256)
void dots_kernel(const __bf16* __restrict__ qT, const __bf16* __restrict__ kkt,
                 float* __restrict__ out)
{
    const int bh   = blockIdx.z;
    const int b    = bh >> 2;
    const int lane = threadIdx.x & 63;
    const int wid  = threadIdx.x >> 6;
    const int i0   = blockIdx.x * 64 + wid * 16;
    const int j0   = blockIdx.y * 32;

    const __bf16* Ab = qT + (size_t)b * 4096 * 160;
    const __bf16* Bb = kkt + (size_t)bh * 160 * 160;
    const int ko = (lane >> 4) << 3;
    const __bf16* pa  = Ab + (size_t)(i0 + (lane & 15)) * 160 + ko;
    const __bf16* pb0 = Bb + (size_t)(j0 + (lane & 15)) * 160 + ko;
    const __bf16* pb1 = pb0 + 16 * 160;

    f32x4 acc0 = {}, acc1 = {};
    #pragma unroll
    for (int m0 = 0; m0 < 160; m0 += 32) {
        bf16x8 a  = *(const bf16x8*)(pa + m0);
        bf16x8 b0 = *(const bf16x8*)(pb0 + m0);
        bf16x8 b1 = *(const bf16x8*)(pb1 + m0);
        acc0 = mfma16(a, b0, acc0);
        acc1 = mfma16(a, b1, acc1);
    }

    #pragma unroll
    for (int r = 0; r < 4; ++r) {
        int i = i0 + ((lane >> 4) << 2) + r;
        int j = j0 + (lane & 15);
        size_t o = ((size_t)bh * 4096 + i) * 160 + j;
        out[o]      = softplus(acc0[r] * SCALE);
        out[o + 16] = softplus(acc1[r] * SCALE);
    }
}

// ---------------------------------------------------------------------------
extern "C" void kernel_launch(void* const* d_in, const int* in_sizes, int n_in,
                              void* d_out, int out_size, void* d_ws, size_t ws_size,
                              hipStream_t stream)
{
    const float* x  = (const float*)d_in[0];
    const float* y  = (const float*)d_in[1];
    const float* Wq = (const float*)d_in[2];
    const float* Wk = (const float*)d_in[3];
    float* out = (float*)d_out;

    // ws layout (bf16): qT[2*4096*160], k[320*4096], kkt[8*160*160],
    //                   xb[320*4096], yb[320*4096]   (~10.9 MB)
    __bf16* qT  = (__bf16*)d_ws;
    __bf16* kbf = qT  + (size_t)2 * 4096 * 160;
    __bf16* kkt = kbf + (size_t)320 * 4096;
    __bf16* xb  = kkt + (size_t)8 * 160 * 160;
    __bf16* yb  = xb  + (size_t)320 * 4096;

    cvt_kernel <<<dim3(640, 2),    256, 0, stream>>>(x, y, xb, yb);
    qk_gemm    <<<dim3(512),       256, 0, stream>>>(yb, xb, Wq, Wk, qT, kbf);
    kkt_kernel <<<dim3(8, 10, 10),  64, 0, stream>>>(kbf, kkt);
    dots_kernel<<<dim3(64, 5, 8),  256, 0, stream>>>(qT, kkt, out);
}

// Round 7
// 112.504 us; speedup vs baseline: 1.2829x; 1.2829x over previous
//
#include <hip/hip_runtime.h>
#include <hip/hip_bf16.h>

// CrossAttention fused pipeline, MI355X (gfx950)
// B=2, N=160, D=4096, H=4, DH=1024, SCALE=1/32 (applied twice)
//
// Traffic model (R1-R6 lesson): time ~ logical bytes / ~5 TB/s. Minimize
// bytes: W read ONCE (nontemporal, 128 MB), A (5.25 MB bf16) re-read only
// 64x/2 = 336->168 MB and pinned L2-resident per XCD (nt-W avoids thrash).
//
// Stage 0: cvt x,y f32 -> bf16 (nt reads)
// Stage 1+2: qk GEMM: BM=320(full M), BN=64, Ksplit=4 (Kc=1024, BK=64).
//   512 blocks = 2/CU; blockIdx&7 = (z,ks) = XCD pin. bf16 partials P[8].
// Stage 2b: reduce 4 partials -> qT[b][d][n] (transposed) and k[320][4096]
// Stage 3: kkt = SCALE * k.k^T per (b,h)      (bf16)
// Stage 4: out = softplus(SCALE * qT @ kkt^T) (f32, nt stores)

typedef __attribute__((ext_vector_type(4))) float  f32x4;
typedef __attribute__((ext_vector_type(8))) __bf16 bf16x8;

#define SCALE 0.03125f

static __device__ __forceinline__ f32x4 mfma16(bf16x8 a, bf16x8 b, f32x4 c) {
    return __builtin_amdgcn_mfma_f32_16x16x32_bf16(a, b, c, 0, 0, 0);
}

static __device__ __forceinline__ bf16x8 pack8(f32x4 a, f32x4 b) {
    bf16x8 r;
    #pragma unroll
    for (int i = 0; i < 4; ++i) { r[i] = (__bf16)a[i]; r[4 + i] = (__bf16)b[i]; }
    return r;
}

static __device__ __forceinline__ bf16x8 pack8f(const float* v) {
    bf16x8 r;
    #pragma unroll
    for (int i = 0; i < 8; ++i) r[i] = (__bf16)v[i];
    return r;
}

static __device__ __forceinline__ float softplus(float x) {
    return fmaxf(x, 0.0f) + log1pf(expf(-fabsf(x)));
}

// ---------------------------------------------------------------------------
// Stage 0: f32 -> bf16 conversion of activations. grid (640, 2), 256 thr.
// ---------------------------------------------------------------------------
__global__ __launch_bounds__(256)
void cvt_kernel(const float* __restrict__ x, const float* __restrict__ y,
                __bf16* __restrict__ xb, __bf16* __restrict__ yb)
{
    const float* src = blockIdx.y ? y : x;
    __bf16* dst = blockIdx.y ? yb : xb;
    size_t i = ((size_t)blockIdx.x * 256 + threadIdx.x) * 8;
    f32x4 a = __builtin_nontemporal_load((const f32x4*)(src + i));
    f32x4 b = __builtin_nontemporal_load((const f32x4*)(src + i + 4));
    *(bf16x8*)(dst + i) = pack8(a, b);
}

// ---------------------------------------------------------------------------
// Stage 1+2: C(320x4096) = A(320x4096,bf16) @ W^T, K-split 4, bf16 partials.
// grid 512 flat: key = blockIdx&7 -> (z = key>>2, ks = key&3)  [XCD pin],
// np = blockIdx>>3 (BN=64 panel). 256 thr = 4 waves, wave tile 80x64
// (acc[5][4]). BK=64, 16 steps. Single-buffer LDS (48 KB, 2 blocks/CU).
// A cached (L2-resident per XCD); W nontemporal (read-once stream).
// Next-step loads issued AFTER the write barrier so the loop-top
// __syncthreads vmcnt-drain is covered by the compute phase.
// ---------------------------------------------------------------------------
__global__ __launch_bounds__(256, 2)
void qk_gemm(const __bf16* __restrict__ yb, const __bf16* __restrict__ xb,
             const float* __restrict__ Wq, const float* __restrict__ Wk,
             __bf16* __restrict__ P)
{
    const int key = blockIdx.x & 7;
    const int z   = key >> 2;             // 0: q (A=yb,W=Wq)  1: k (A=xb,W=Wk)
    const int ks  = key & 3;
    const int np  = blockIdx.x >> 3;      // 0..63
    const int bn  = np * 64;
    const int kc  = ks * 1024;

    __shared__ __bf16 lA[320 * 64];       // 40 KB
    __shared__ __bf16 lW[64 * 64];        // 8 KB

    const int tid  = threadIdx.x;
    const int lane = tid & 63;
    const int wid  = tid >> 6;            // 0..3 : rows wid*80..+79
    const int li   = lane & 15;
    const int lk   = lane >> 4;

    const __bf16* __restrict__ Ab = z ? xb : yb;   // [320][4096]
    const float*  __restrict__ Wm = z ? Wk : Wq;

    // ---- A staging: 10 pieces of 16B; piece p: row p*32+(tid>>3), slot tid&7
    const int arow  = tid >> 3;           // 0..31
    const int aslot = tid & 7;
    const int aswz  = (aslot ^ (arow & 7)) * 8;
    const __bf16* ag = Ab + (size_t)arow * 4096 + kc + aslot * 8;

    // ---- W staging: row tid>>2 (0..63), 16 f32 at (tid&3)*16 ----
    const int wrow = tid >> 2;
    const float* wg = Wm + (size_t)(bn + wrow) * 4096 + kc + (tid & 3) * 16;
    const int wsl0 = ((((tid & 3) << 1))     ^ (wrow & 7)) * 8;
    const int wsl1 = ((((tid & 3) << 1) | 1) ^ (wrow & 7)) * 8;

    f32x4 acc[5][4] = {};
    bf16x8 areg[10];
    f32x4  wreg[4];

    // prologue: load step 0
    #pragma unroll
    for (int p = 0; p < 10; ++p)
        areg[p] = *(const bf16x8*)(ag + (size_t)p * 32 * 4096);
    #pragma unroll
    for (int i = 0; i < 4; ++i)
        wreg[i] = __builtin_nontemporal_load((const f32x4*)(wg + i * 4));

    for (int s = 0; s < 16; ++s) {
        __syncthreads();                  // prev-step LDS reads done (+vm drain)
        #pragma unroll
        for (int p = 0; p < 10; ++p)
            *(bf16x8*)&lA[(p * 32 + arow) * 64 + aswz] = areg[p];
        *(bf16x8*)&lW[wrow * 64 + wsl0] = pack8(wreg[0], wreg[1]);
        *(bf16x8*)&lW[wrow * 64 + wsl1] = pack8(wreg[2], wreg[3]);
        __syncthreads();                  // writes visible

        if (s < 15) {                     // issue next-step loads, then compute
            #pragma unroll
            for (int p = 0; p < 10; ++p)
                areg[p] = *(const bf16x8*)(ag + (size_t)p * 32 * 4096 + (s + 1) * 64);
            #pragma unroll
            for (int i = 0; i < 4; ++i)
                wreg[i] = __builtin_nontemporal_load((const f32x4*)(wg + (s + 1) * 64 + i * 4));
        }

        #pragma unroll
        for (int kk = 0; kk < 2; ++kk) {
            const int slot = kk * 4 + lk;
            bf16x8 wf[4], af[5];
            #pragma unroll
            for (int jn = 0; jn < 4; ++jn) {
                const int j = jn * 16 + li;
                wf[jn] = *(const bf16x8*)&lW[j * 64 + ((slot ^ (j & 7)) << 3)];
            }
            #pragma unroll
            for (int m = 0; m < 5; ++m) {
                const int rr = wid * 80 + m * 16 + li;
                af[m] = *(const bf16x8*)&lA[rr * 64 + ((slot ^ (rr & 7)) << 3)];
            }
            __builtin_amdgcn_s_setprio(1);
            #pragma unroll
            for (int m = 0; m < 5; ++m)
                #pragma unroll
                for (int jn = 0; jn < 4; ++jn)
                    acc[m][jn] = mfma16(af[m], wf[jn], acc[m][jn]);
            __builtin_amdgcn_s_setprio(0);
        }
    }

    // Epilogue: bf16 partials, nt stores. C/D: col=li, row=lk*4+r.
    __bf16* Pz = P + (size_t)key * 320 * 4096;
    #pragma unroll
    for (int m = 0; m < 5; ++m) {
        const int row0 = wid * 80 + m * 16 + lk * 4;
        #pragma unroll
        for (int jn = 0; jn < 4; ++jn) {
            const int col = bn + jn * 16 + li;
            #pragma unroll
            for (int r = 0; r < 4; ++r)
                __builtin_nontemporal_store((__bf16)acc[m][jn][r],
                                            &Pz[(size_t)(row0 + r) * 4096 + col]);
        }
    }
}

// ---------------------------------------------------------------------------
// Stage 2b: reduce 4 bf16 partials -> qT (transposed) and k.
// grid (64 col-tiles, 5 row-tiles, 2 z), 256 threads, 64x64 tiles.
// ---------------------------------------------------------------------------
__global__ __launch_bounds__(256)
void reduce_kernel(const __bf16* __restrict__ P,
                   __bf16* __restrict__ qT, __bf16* __restrict__ kout)
{
    const int z    = blockIdx.z;
    const int col0 = blockIdx.x * 64;
    const int row0 = blockIdx.y * 64;
    const __bf16* P0 = P + ((size_t)z * 4 + 0) * 320 * 4096;
    const __bf16* P1 = P + ((size_t)z * 4 + 1) * 320 * 4096;
    const __bf16* P2 = P + ((size_t)z * 4 + 2) * 320 * 4096;
    const __bf16* P3 = P + ((size_t)z * 4 + 3) * 320 * 4096;

    const int t  = threadIdx.x;
    const int r  = t >> 2;                // 0..63
    const int cc = (t & 3) * 16;          // 0,16,32,48

    float v[16];
    {
        size_t base = (size_t)(row0 + r) * 4096 + col0 + cc;
        #pragma unroll
        for (int i = 0; i < 2; ++i) {
            bf16x8 a = *(const bf16x8*)(P0 + base + i * 8);
            bf16x8 b = *(const bf16x8*)(P1 + base + i * 8);
            bf16x8 c = *(const bf16x8*)(P2 + base + i * 8);
            bf16x8 d = *(const bf16x8*)(P3 + base + i * 8);
            #pragma unroll
            for (int j = 0; j < 8; ++j)
                v[i * 8 + j] = (float)a[j] + (float)b[j] + (float)c[j] + (float)d[j];
        }
    }

    if (z == 1) {  // k: row-major, direct
        __bf16* dst = kout + (size_t)(row0 + r) * 4096 + col0 + cc;
        *(bf16x8*)dst       = pack8f(v);
        *(bf16x8*)(dst + 8) = pack8f(v + 8);
        return;
    }

    // q: transpose via LDS -> qT[b][col][ri]
    __shared__ float lt[64][65];
    #pragma unroll
    for (int i = 0; i < 16; ++i) lt[r][cc + i] = v[i];
    __syncthreads();

    const int col = t & 63;
    const int rr0 = (t >> 6) * 16;
    float w[16];
    #pragma unroll
    for (int i = 0; i < 16; ++i) w[i] = lt[rr0 + i][col];

    const int gr = row0 + rr0;            // multiple of 16; never straddles 160
    const int b  = gr >= 160;
    const int ri = gr - b * 160;
    __bf16* dst = qT + (size_t)b * 4096 * 160 + (size_t)(col0 + col) * 160 + ri;
    *(bf16x8*)dst       = pack8f(w);
    *(bf16x8*)(dst + 8) = pack8f(w + 8);
}

// ---------------------------------------------------------------------------
// Stage 3: kkt (symmetric). One wave per 16x16 output tile, K=1024.
// ---------------------------------------------------------------------------
__global__ __launch_bounds__(64)
void kkt_kernel(const __bf16* __restrict__ kmat, __bf16* __restrict__ kkt)
{
    const int bh = blockIdx.x;            // b*4 + h
    const int b  = bh >> 2, h = bh & 3;
    const int i0 = blockIdx.y * 16;
    const int j0 = blockIdx.z * 16;
    const int lane = threadIdx.x;

    const __bf16* base = kmat + (size_t)b * 160 * 4096 + h * 1024;
    const int ko = (lane >> 4) << 3;
    const __bf16* pa = base + (size_t)(i0 + (lane & 15)) * 4096 + ko;
    const __bf16* pb = base + (size_t)(j0 + (lane & 15)) * 4096 + ko;

    f32x4 acc = {};
    #pragma unroll 4
    for (int kk = 0; kk < 1024; kk += 32) {
        bf16x8 a  = *(const bf16x8*)(pa + kk);
        bf16x8 bb = *(const bf16x8*)(pb + kk);
        acc = mfma16(a, bb, acc);
    }

    #pragma unroll
    for (int r = 0; r < 4; ++r) {
        int i = i0 + ((lane >> 4) << 2) + r;
        int j = j0 + (lane & 15);
        kkt[((size_t)bh * 160 + i) * 160 + j] = (__bf16)(acc[r] * SCALE);
    }
}

// ---------------------------------------------------------------------------
// Stage 4: dots + softplus. Per (b,h): C(4096x160) = qT[b] @ kkt[b,h]^T. K=160.
// ---------------------------------------------------------------------------
__global__ __launch_bounds__(256)
void dots_kernel(const __bf16* __restrict__ qT, const __bf16* __restrict__ kkt,
                 float* __restrict__ out)
{
    const int bh   = blockIdx.z;
    const int b    = bh >> 2;
    const int lane = threadIdx.x & 63;
    const int wid  = threadIdx.x >> 6;
    const int i0   = blockIdx.x * 64 + wid * 16;
    const int j0   = blockIdx.y * 32;

    const __bf16* Ab = qT + (size_t)b * 4096 * 160;
    const __bf16* Bb = kkt + (size_t)bh * 160 * 160;
    const int ko = (lane >> 4) << 3;
    const __bf16* pa  = Ab + (size_t)(i0 + (lane & 15)) * 160 + ko;
    const __bf16* pb0 = Bb + (size_t)(j0 + (lane & 15)) * 160 + ko;
    const __bf16* pb1 = pb0 + 16 * 160;

    f32x4 acc0 = {}, acc1 = {};
    #pragma unroll
    for (int m0 = 0; m0 < 160; m0 += 32) {
        bf16x8 a  = *(const bf16x8*)(pa + m0);
        bf16x8 b0 = *(const bf16x8*)(pb0 + m0);
        bf16x8 b1 = *(const bf16x8*)(pb1 + m0);
        acc0 = mfma16(a, b0, acc0);
        acc1 = mfma16(a, b1, acc1);
    }

    #pragma unroll
    for (int r = 0; r < 4; ++r) {
        int i = i0 + ((lane >> 4) << 2) + r;
        int j = j0 + (lane & 15);
        size_t o = ((size_t)bh * 4096 + i) * 160 + j;
        __builtin_nontemporal_store(softplus(acc0[r] * SCALE), &out[o]);
        __builtin_nontemporal_store(softplus(acc1[r] * SCALE), &out[o + 16]);
    }
}

// ---------------------------------------------------------------------------
extern "C" void kernel_launch(void* const* d_in, const int* in_sizes, int n_in,
                              void* d_out, int out_size, void* d_ws, size_t ws_size,
                              hipStream_t stream)
{
    const float* x  = (const float*)d_in[0];
    const float* y  = (const float*)d_in[1];
    const float* Wq = (const float*)d_in[2];
    const float* Wk = (const float*)d_in[3];
    float* out = (float*)d_out;

    // ws (bf16): qT[2*4096*160], k[320*4096], kkt[8*160*160],
    //            xb[320*4096], yb[320*4096], P[8][320*4096]  (~32 MB)
    __bf16* qT  = (__bf16*)d_ws;
    __bf16* kbf = qT  + (size_t)2 * 4096 * 160;
    __bf16* kkt = kbf + (size_t)320 * 4096;
    __bf16* xb  = kkt + (size_t)8 * 160 * 160;
    __bf16* yb  = xb  + (size_t)320 * 4096;
    __bf16* P   = yb  + (size_t)320 * 4096;

    cvt_kernel   <<<dim3(640, 2),    256, 0, stream>>>(x, y, xb, yb);
    qk_gemm      <<<dim3(512),       256, 0, stream>>>(yb, xb, Wq, Wk, P);
    reduce_kernel<<<dim3(64, 5, 2),  256, 0, stream>>>(P, qT, kbf);
    kkt_kernel   <<<dim3(8, 10, 10),  64, 0, stream>>>(kbf, kkt);
    dots_kernel  <<<dim3(64, 5, 8),  256, 0, stream>>>(qT, kkt, out);
}